// Round 1
// baseline (231.364 us; speedup 1.0000x reference)
//
#include <hip/hip_runtime.h>

// SpikingNeuralNetwork: fc1 (split-bf16 MFMA GEMM, fused LIF scan) + sparse fc2.
// Precision: x = x_hi + x_lo (bf16 each), W1 likewise; cur = hi*hi + hi*lo + lo*hi
// reproduces fp32 cur to ~4e-6 -> no spike flips vs fp32 reference.

typedef __attribute__((ext_vector_type(4))) float f32x4;
typedef __attribute__((ext_vector_type(8))) short s16x8;

#define GPTR(p) ((const __attribute__((address_space(1))) void*)(p))
#define SPTR(p) ((__attribute__((address_space(3))) void*)(p))

static constexpr int Bsz = 64, Tsz = 256, Isz = 1024, Hsz = 2048, Osz = 1024;
static constexpr int KB = 32;   // fp32 k per staged block
static constexpr int NB = 64;   // h columns per workgroup

__device__ __forceinline__ unsigned short f2bf(float f) {
  unsigned u = __float_as_uint(f);
  u += 0x7FFFu + ((u >> 16) & 1u);
  return (unsigned short)(u >> 16);
}
__device__ __forceinline__ float bf2f(unsigned short h) {
  return __uint_as_float(((unsigned)h) << 16);
}

// ---------------- kernel 1: split x into hi/lo bf16 ----------------
__global__ void split_x_kernel(const float* __restrict__ x,
                               unsigned short* __restrict__ hi,
                               unsigned short* __restrict__ lo) {
  const long i = (long)blockIdx.x * 256 + threadIdx.x;  // one float4 each
  const float4 v = ((const float4*)x)[i];
  const unsigned short hx = f2bf(v.x), hy = f2bf(v.y), hz = f2bf(v.z), hw = f2bf(v.w);
  ushort4 H, L;
  H.x = hx; H.y = hy; H.z = hz; H.w = hw;
  L.x = f2bf(v.x - bf2f(hx));
  L.y = f2bf(v.y - bf2f(hy));
  L.z = f2bf(v.z - bf2f(hz));
  L.w = f2bf(v.w - bf2f(hw));
  ((ushort4*)hi)[i] = H;
  ((ushort4*)lo)[i] = L;
}

// ------- kernel 2: W1 [I][H] -> transposed bf16 hi/lo [H][I] -------
__global__ void w1_transpose_split_kernel(const float* __restrict__ W1,
                                          unsigned short* __restrict__ wh,
                                          unsigned short* __restrict__ wl) {
  __shared__ float tile[32][33];
  const int h0 = blockIdx.x * 32;  // H dim
  const int i0 = blockIdx.y * 32;  // I dim
  const int c = threadIdx.x & 31;
  const int r4 = threadIdx.x >> 5;  // 0..7
#pragma unroll
  for (int s = 0; s < 4; ++s) {
    const int r = r4 + s * 8;
    tile[r][c] = W1[(long)(i0 + r) * Hsz + h0 + c];
  }
  __syncthreads();
#pragma unroll
  for (int s = 0; s < 4; ++s) {
    const int hr = r4 + s * 8;
    const float v = tile[c][hr];  // = W1[i0+c][h0+hr]
    const unsigned short hh = f2bf(v);
    wh[(long)(h0 + hr) * Isz + i0 + c] = hh;
    wl[(long)(h0 + hr) * Isz + i0 + c] = f2bf(v - bf2f(hh));
  }
}

// ---- kernel 3: fused GEMM1 (split-bf16 MFMA) + LIF scan over T ----
// grid (H/NB, B), 256 threads (4 waves). Wave w owns t-rows [64w,64w+64).
__global__ __launch_bounds__(256, 3) void gemm1_scan_kernel(
    const unsigned short* __restrict__ xh, const unsigned short* __restrict__ xl,
    const unsigned short* __restrict__ wth, const unsigned short* __restrict__ wtl,
    const float* __restrict__ b1, float* __restrict__ spk) {
  __shared__ __align__(16) unsigned short lds[2 * Tsz * KB + 2 * NB * KB];  // 40KB
  unsigned short* ldsAh = lds;
  unsigned short* ldsAl = lds + Tsz * KB;
  unsigned short* ldsBh = lds + 2 * Tsz * KB;
  unsigned short* ldsBl = lds + 2 * Tsz * KB + NB * KB;

  const int tid = threadIdx.x;
  const int w = tid >> 6;
  const int l = tid & 63;
  const int b = blockIdx.y;
  const int hblk = blockIdx.x * NB;

  const int lr = l >> 2;         // row within 16-row chunk (4 lanes/row)
  const int lc = (l & 3) * 8;    // k element offset within row

  f32x4 acc[4][4];
#pragma unroll
  for (int i = 0; i < 4; ++i)
#pragma unroll
    for (int j = 0; j < 4; ++j)
      acc[i][j] = f32x4{0.f, 0.f, 0.f, 0.f};

  const long rowA0 = (long)b * Tsz;

  for (int kb = 0; kb < Isz / KB; ++kb) {
    const int k0 = kb * KB;
    // stage A (x) hi+lo: wave w stages its own 64 t-rows, 4 chunks of 16 rows
#pragma unroll
    for (int c = 0; c < 4; ++c) {
      const int rloc = w * 64 + c * 16;
      const unsigned short* gh = xh + (rowA0 + rloc + lr) * Isz + k0 + lc;
      const unsigned short* gl = xl + (rowA0 + rloc + lr) * Isz + k0 + lc;
      __builtin_amdgcn_global_load_lds(GPTR(gh), SPTR(ldsAh + rloc * KB), 16, 0, 0);
      __builtin_amdgcn_global_load_lds(GPTR(gl), SPTR(ldsAl + rloc * KB), 16, 0, 0);
    }
    // stage B (W1^T) hi+lo: wave w stages h-rows [16w,16w+16)
    {
      const int hloc = w * 16;
      const unsigned short* gh = wth + (long)(hblk + hloc + lr) * Isz + k0 + lc;
      const unsigned short* gl = wtl + (long)(hblk + hloc + lr) * Isz + k0 + lc;
      __builtin_amdgcn_global_load_lds(GPTR(gh), SPTR(ldsBh + hloc * KB), 16, 0, 0);
      __builtin_amdgcn_global_load_lds(GPTR(gl), SPTR(ldsBl + hloc * KB), 16, 0, 0);
    }
    __syncthreads();  // drains vmcnt before any wave reads LDS

    // A fragments: row = w*64 + mi*16 + (l&15), k = (l>>4)*8 + j
    s16x8 ah[4], al[4];
    const int arow = w * 64 + (l & 15);
    const int koff = (l >> 4) * 8;
#pragma unroll
    for (int mi = 0; mi < 4; ++mi) {
      const int off = (arow + mi * 16) * KB + koff;
      ah[mi] = *(const s16x8*)(ldsAh + off);
      al[mi] = *(const s16x8*)(ldsAl + off);
    }
#pragma unroll
    for (int ni = 0; ni < 4; ++ni) {
      const int boff = (ni * 16 + (l & 15)) * KB + koff;
      const s16x8 bh = *(const s16x8*)(ldsBh + boff);
      const s16x8 bl = *(const s16x8*)(ldsBl + boff);
#pragma unroll
      for (int mi = 0; mi < 4; ++mi) {
        acc[mi][ni] = __builtin_amdgcn_mfma_f32_16x16x32_bf16(ah[mi], bh, acc[mi][ni], 0, 0, 0);
        acc[mi][ni] = __builtin_amdgcn_mfma_f32_16x16x32_bf16(ah[mi], bl, acc[mi][ni], 0, 0, 0);
        acc[mi][ni] = __builtin_amdgcn_mfma_f32_16x16x32_bf16(al[mi], bh, acc[mi][ni], 0, 0, 0);
      }
    }
    __syncthreads();  // before next stage overwrites LDS
  }

  // ---- LIF scan: 4 phases x 64 timesteps through an LDS buffer ----
  float* scanbuf = (float*)lds;  // [64][NB] f32 = 16KB, aliases staging LDS
  float memv = 0.f;
  int fired = 0;
  const float b1v = (tid < NB) ? b1[hblk + tid] : 0.f;

  for (int p = 0; p < 4; ++p) {
    if (w == p) {
      // C/D layout: col = ni*16 + (l&15); row = mi*16 + (l>>4)*4 + r
#pragma unroll
      for (int mi = 0; mi < 4; ++mi)
#pragma unroll
        for (int ni = 0; ni < 4; ++ni) {
          const int col = ni * 16 + (l & 15);
          const int trow = mi * 16 + (l >> 4) * 4;
#pragma unroll
          for (int r = 0; r < 4; ++r)
            scanbuf[(trow + r) * NB + col] = acc[mi][ni][r];
        }
    }
    __syncthreads();
    if (tid < NB) {
      for (int t = 0; t < 64; ++t) {
        const float c = scanbuf[t * NB + tid] + b1v;
        memv = memv * 0.9f + c * 0.1f;
        fired = memv > 1.0f;
        if (fired) memv = 0.f;
      }
    }
    __syncthreads();
  }
  if (tid < NB) spk[(long)b * Hsz + hblk + tid] = fired ? 1.0f : 0.0f;
}

// ------- kernel 4: out = spk @ W2 + b2, exploiting spike sparsity -------
__global__ void gemm2_kernel(const float* __restrict__ spk, const float* __restrict__ W2,
                             const float* __restrict__ b2, float* __restrict__ out) {
  __shared__ int s_cnt[256];
  __shared__ int s_off[257];
  __shared__ int s_list[Hsz];
  const int b = blockIdx.x;
  const int tid = threadIdx.x;
  int hs[8];
  int c = 0;
#pragma unroll
  for (int e = 0; e < 8; ++e) {
    const int h = tid * 8 + e;
    if (spk[(long)b * Hsz + h] > 0.5f) hs[c++] = h;
  }
  s_cnt[tid] = c;
  __syncthreads();
  if (tid == 0) {
    int s = 0;
    for (int i = 0; i < 256; ++i) { s_off[i] = s; s += s_cnt[i]; }
    s_off[256] = s;
  }
  __syncthreads();
  {
    const int base = s_off[tid];
    for (int i = 0; i < c; ++i) s_list[base + i] = hs[i];
  }
  __syncthreads();
  const int total = s_off[256];
#pragma unroll
  for (int q = 0; q < 4; ++q) {
    const int o = q * 256 + tid;
    float v = b2[o];
    for (int i = 0; i < total; ++i) v += W2[(long)s_list[i] * Osz + o];
    out[(long)b * Osz + o] = v;
  }
}

extern "C" void kernel_launch(void* const* d_in, const int* in_sizes, int n_in,
                              void* d_out, int out_size, void* d_ws, size_t ws_size,
                              hipStream_t stream) {
  const float* x  = (const float*)d_in[0];
  const float* W1 = (const float*)d_in[1];
  const float* b1 = (const float*)d_in[2];
  const float* W2 = (const float*)d_in[3];
  const float* b2 = (const float*)d_in[4];
  float* out = (float*)d_out;

  // workspace layout (total ~72.5 MB)
  unsigned short* xh = (unsigned short*)d_ws;                    // [16384][1024] bf16
  unsigned short* xl = xh + (long)Bsz * Tsz * Isz;               // [16384][1024]
  unsigned short* wh = xl + (long)Bsz * Tsz * Isz;               // [2048][1024] (W1^T)
  unsigned short* wl = wh + (long)Hsz * Isz;                     // [2048][1024]
  float* spk = (float*)(wl + (long)Hsz * Isz);                   // [64][2048]

  // 1) split x into bf16 hi/lo
  split_x_kernel<<<(Bsz * Tsz * Isz) / (256 * 4), 256, 0, stream>>>(x, xh, xl);
  // 2) transpose+split W1
  w1_transpose_split_kernel<<<dim3(Hsz / 32, Isz / 32), 256, 0, stream>>>(W1, wh, wl);
  // 3) fused GEMM1 + LIF scan -> spk_last
  gemm1_scan_kernel<<<dim3(Hsz / NB, Bsz), 256, 0, stream>>>(xh, xl, wh, wl, b1, spk);
  // 4) sparse fc2
  gemm2_kernel<<<Bsz, 256, 0, stream>>>(spk, W2, b2, out);
}

// Round 2
// 229.143 us; speedup vs baseline: 1.0097x; 1.0097x over previous
//
#include <hip/hip_runtime.h>

// SpikingNeuralNetwork: fc1 (split-bf16 MFMA GEMM, fused LIF scan) + sparse fc2.
// R2: 8-phase-style schedule (T3+T4) + LDS XOR swizzle (T2, both-sides w/
// global_load_lds) + setprio (T5) + bijective XCD swizzle (T1).
// Precision: x = x_hi + x_lo (bf16 each), W1 likewise; cur = hi*hi + hi*lo + lo*hi
// reproduces fp32 cur to ~4e-6 -> no spike flips vs fp32 reference (R1: absmax 0.0).

typedef __attribute__((ext_vector_type(4))) float f32x4;
typedef __attribute__((ext_vector_type(8))) short s16x8;

#define GPTR(p) ((const __attribute__((address_space(1))) void*)(p))
#define SPTR(p) ((__attribute__((address_space(3))) void*)(p))

static constexpr int Bsz = 64, Tsz = 256, Isz = 1024, Hsz = 2048, Osz = 1024;
static constexpr int BM = 256, BN = 128, BK = 32;  // block tile (T x H), fp32-k per K-tile
static constexpr int NKT = Isz / BK;               // 32 K-tiles
static constexpr int AHALF = (BM / 2) * BK;        // 4096 elements
static constexpr int ABUF = BM * BK;               // 8192 elements (one of hi/lo)
static constexpr int BBUF = BN * BK;               // 4096
static constexpr int BUFSZ = 2 * ABUF + 2 * BBUF;  // 24576 ushorts = 48KB per K-tile buffer

__device__ __forceinline__ unsigned short f2bf(float f) {
  unsigned u = __float_as_uint(f);
  u += 0x7FFFu + ((u >> 16) & 1u);
  return (unsigned short)(u >> 16);
}
__device__ __forceinline__ float bf2f(unsigned short h) {
  return __uint_as_float(((unsigned)h) << 16);
}

// ---------------- kernel 1: split x into hi/lo bf16 ----------------
__global__ void split_x_kernel(const float* __restrict__ x,
                               unsigned short* __restrict__ hi,
                               unsigned short* __restrict__ lo) {
  const long i = (long)blockIdx.x * 256 + threadIdx.x;  // one float4 each
  const float4 v = ((const float4*)x)[i];
  const unsigned short hx = f2bf(v.x), hy = f2bf(v.y), hz = f2bf(v.z), hw = f2bf(v.w);
  ushort4 H, L;
  H.x = hx; H.y = hy; H.z = hz; H.w = hw;
  L.x = f2bf(v.x - bf2f(hx));
  L.y = f2bf(v.y - bf2f(hy));
  L.z = f2bf(v.z - bf2f(hz));
  L.w = f2bf(v.w - bf2f(hw));
  ((ushort4*)hi)[i] = H;
  ((ushort4*)lo)[i] = L;
}

// ------- kernel 2: W1 [I][H] -> transposed bf16 hi/lo [H][I] -------
__global__ void w1_transpose_split_kernel(const float* __restrict__ W1,
                                          unsigned short* __restrict__ wh,
                                          unsigned short* __restrict__ wl) {
  __shared__ float tile[32][33];
  const int h0 = blockIdx.x * 32;  // H dim
  const int i0 = blockIdx.y * 32;  // I dim
  const int c = threadIdx.x & 31;
  const int r4 = threadIdx.x >> 5;  // 0..7
#pragma unroll
  for (int s = 0; s < 4; ++s) {
    const int r = r4 + s * 8;
    tile[r][c] = W1[(long)(i0 + r) * Hsz + h0 + c];
  }
  __syncthreads();
#pragma unroll
  for (int s = 0; s < 4; ++s) {
    const int hr = r4 + s * 8;
    const float v = tile[c][hr];  // = W1[i0+c][h0+hr]
    const unsigned short hh = f2bf(v);
    wh[(long)(h0 + hr) * Isz + i0 + c] = hh;
    wl[(long)(h0 + hr) * Isz + i0 + c] = f2bf(v - bf2f(hh));
  }
}

// ---- kernel 3: fused GEMM1 (split-bf16 MFMA, 8-phase schedule) + LIF scan ----
// grid (16, 64) = 1024 wgs; 512 threads = 8 waves (4M x 2N); wave tile 64x64.
// Triple-buffered LDS (144KB), counted vmcnt(6), 4 phases/K-tile, 12 MFMA/phase.
__global__ __launch_bounds__(512, 2) void gemm1_scan_kernel(
    const unsigned short* __restrict__ xh, const unsigned short* __restrict__ xl,
    const unsigned short* __restrict__ wth, const unsigned short* __restrict__ wtl,
    const float* __restrict__ b1, float* __restrict__ spk) {
  __shared__ __align__(16) unsigned short lds[3 * BUFSZ];  // 144KB

  const int tid = threadIdx.x;
  const int l = tid & 63;
  const int w = tid >> 6;
  const int wm = w >> 1;  // 0..3 (M)
  const int wn = w & 1;   // 0..1 (N)

  // T1: bijective XCD swizzle — each XCD gets 8 contiguous batches (A-panel L2 reuse)
  const int orig = blockIdx.y * 16 + blockIdx.x;      // dispatch-linear (gridDim.x=16)
  const int nid = (orig & 7) * 128 + (orig >> 3);     // 1024 wgs, 8 XCDs, bijective
  const int b = nid >> 4;                             // 0..63
  const int hblk = (nid & 15) * BN;                   // 0..1920

  // --- staging geometry (T21: linear LDS dest + inverse-swizzled global source) ---
  // LDS row stride = BK=32 el = 64B = 4 chunks of 16B. Swizzle: chunk' = chunk ^ ((row>>1)&3).
  const int srow = tid >> 2;                           // 0..127
  const int gch = (tid & 3) ^ ((tid >> 3) & 3);        // source chunk (pre-swizzled)
  const unsigned short* gAh0 = xh + ((long)(b * Tsz) + srow) * Isz + gch * 8;
  const unsigned short* gAh1 = xh + ((long)(b * Tsz) + 128 + srow) * Isz + gch * 8;
  const unsigned short* gAl0 = xl + ((long)(b * Tsz) + srow) * Isz + gch * 8;
  const unsigned short* gAl1 = xl + ((long)(b * Tsz) + 128 + srow) * Isz + gch * 8;
  const unsigned short* gBh = wth + ((long)(hblk + srow)) * Isz + gch * 8;
  const unsigned short* gBl = wtl + ((long)(hblk + srow)) * Isz + gch * 8;
  const int ldst = tid * 8;  // element offset within a (half-)buffer; per-wave linear

#define ST_AH(Q, KT) do { unsigned short* d_ = lds + (Q) * BUFSZ + ldst;                        \
    __builtin_amdgcn_global_load_lds(GPTR(gAh0 + (KT) * BK), SPTR(d_), 16, 0, 0);               \
    __builtin_amdgcn_global_load_lds(GPTR(gAh1 + (KT) * BK), SPTR(d_ + AHALF), 16, 0, 0); } while (0)
#define ST_AL(Q, KT) do { unsigned short* d_ = lds + (Q) * BUFSZ + ABUF + ldst;                 \
    __builtin_amdgcn_global_load_lds(GPTR(gAl0 + (KT) * BK), SPTR(d_), 16, 0, 0);               \
    __builtin_amdgcn_global_load_lds(GPTR(gAl1 + (KT) * BK), SPTR(d_ + AHALF), 16, 0, 0); } while (0)
#define ST_BH(Q, KT) do { unsigned short* d_ = lds + (Q) * BUFSZ + 2 * ABUF + ldst;             \
    __builtin_amdgcn_global_load_lds(GPTR(gBh + (KT) * BK), SPTR(d_), 16, 0, 0); } while (0)
#define ST_BL(Q, KT) do { unsigned short* d_ = lds + (Q) * BUFSZ + 2 * ABUF + BBUF + ldst;      \
    __builtin_amdgcn_global_load_lds(GPTR(gBl + (KT) * BK), SPTR(d_), 16, 0, 0); } while (0)

  // --- fragment read addressing (swizzled reads; xr = (row>>1)&3 = (l>>1)&3) ---
  const int swz = ((l >> 4) ^ ((l >> 1) & 3)) * 8;
  const int aBase = (wm * 64 + (l & 15)) * BK + swz;  // + mi*512
  const int bBase = (wn * 64 + (l & 15)) * BK + swz;  // + ni*512

  f32x4 acc[4][4];
#pragma unroll
  for (int i = 0; i < 4; ++i)
#pragma unroll
    for (int j = 0; j < 4; ++j) acc[i][j] = f32x4{0.f, 0.f, 0.f, 0.f};

  s16x8 Ah[4], Al[4], Bh[4], Bl[4];

#define MM(MI, NI) do {                                                                          \
    acc[MI][NI] = __builtin_amdgcn_mfma_f32_16x16x32_bf16(Ah[MI], Bh[NI], acc[MI][NI], 0, 0, 0); \
    acc[MI][NI] = __builtin_amdgcn_mfma_f32_16x16x32_bf16(Ah[MI], Bl[NI], acc[MI][NI], 0, 0, 0); \
    acc[MI][NI] = __builtin_amdgcn_mfma_f32_16x16x32_bf16(Al[MI], Bh[NI], acc[MI][NI], 0, 0, 0); \
  } while (0)

#define BAR() __builtin_amdgcn_s_barrier()
#define LGKM0() do { asm volatile("s_waitcnt lgkmcnt(0)" ::: "memory");                          \
    __builtin_amdgcn_sched_barrier(0); } while (0)

  // --- prologue: stage K-tiles 0 and 1 ---
  ST_AH(0, 0); ST_AL(0, 0); ST_BH(0, 0); ST_BL(0, 0);
  ST_AH(1, 1); ST_AL(1, 1); ST_BH(1, 1); ST_BL(1, 1);
  asm volatile("s_waitcnt vmcnt(6)" ::: "memory");  // tile 0 landed (6 of tile 1 in flight)
  BAR();

  int q = 0;  // read buffer
  for (int kt = 0; kt < NKT; ++kt) {
    const unsigned short* pAh = lds + q * BUFSZ;
    const unsigned short* pAl = pAh + ABUF;
    const unsigned short* pBh = pAh + 2 * ABUF;
    const unsigned short* pBl = pBh + BBUF;
    const int qn = (q >= 1) ? q - 1 : 2;  // (q+2)%3 — stage target
    const bool st = (kt + 2) < NKT;
    const int kst = kt + 2;

    // ---- phase 0: read A0,A1,B0,B1 ; stage Ah(kt+2) ; MFMA quad (mi 0-1, ni 0-1) ----
    Ah[0] = *(const s16x8*)(pAh + aBase);
    Al[0] = *(const s16x8*)(pAl + aBase);
    Ah[1] = *(const s16x8*)(pAh + aBase + 512);
    Al[1] = *(const s16x8*)(pAl + aBase + 512);
    Bh[0] = *(const s16x8*)(pBh + bBase);
    Bl[0] = *(const s16x8*)(pBl + bBase);
    Bh[1] = *(const s16x8*)(pBh + bBase + 512);
    Bl[1] = *(const s16x8*)(pBl + bBase + 512);
    if (st) ST_AH(qn, kst);
    BAR();
    LGKM0();
    __builtin_amdgcn_s_setprio(1);
    MM(0, 0); MM(0, 1); MM(1, 0); MM(1, 1);
    __builtin_amdgcn_s_setprio(0);
    BAR();

    // ---- phase 1: read B2,B3 ; stage Al(kt+2) ; MFMA quad (mi 0-1, ni 2-3) ----
    Bh[2] = *(const s16x8*)(pBh + bBase + 1024);
    Bl[2] = *(const s16x8*)(pBl + bBase + 1024);
    Bh[3] = *(const s16x8*)(pBh + bBase + 1536);
    Bl[3] = *(const s16x8*)(pBl + bBase + 1536);
    if (st) ST_AL(qn, kst);
    BAR();
    LGKM0();
    __builtin_amdgcn_s_setprio(1);
    MM(0, 2); MM(0, 3); MM(1, 2); MM(1, 3);
    __builtin_amdgcn_s_setprio(0);
    BAR();

    // ---- phase 2: read A2,A3 ; stage Bh(kt+2) ; MFMA quad (mi 2-3, ni 0-1) ----
    Ah[2] = *(const s16x8*)(pAh + aBase + 1024);
    Al[2] = *(const s16x8*)(pAl + aBase + 1024);
    Ah[3] = *(const s16x8*)(pAh + aBase + 1536);
    Al[3] = *(const s16x8*)(pAl + aBase + 1536);
    if (st) ST_BH(qn, kst);
    BAR();
    LGKM0();
    __builtin_amdgcn_s_setprio(1);
    MM(2, 0); MM(2, 1); MM(3, 0); MM(3, 1);
    __builtin_amdgcn_s_setprio(0);
    BAR();

    // ---- phase 3: stage Bl(kt+2) ; MFMA quad (mi 2-3, ni 2-3) ; counted vmcnt ----
    if (st) ST_BL(qn, kst);
    BAR();
    LGKM0();
    __builtin_amdgcn_s_setprio(1);
    MM(2, 2); MM(2, 3); MM(3, 2); MM(3, 3);
    __builtin_amdgcn_s_setprio(0);
    if (kt < NKT - 2) asm volatile("s_waitcnt vmcnt(6)" ::: "memory");  // next tile landed
    else              asm volatile("s_waitcnt vmcnt(0)" ::: "memory");  // tail drain
    BAR();

    q = (q == 2) ? 0 : q + 1;
  }

  // ---- LIF scan: 4 phases x 64 timesteps through an LDS buffer ----
  __syncthreads();
  float* scanbuf = reinterpret_cast<float*>(lds);  // [64][132] f32 = 33.8KB (padded stride)
  float memv = 0.f;
  int fired = 0;
  const float b1v = b1[hblk + ((tid < BN) ? tid : 0)];

  for (int p = 0; p < 4; ++p) {
    if (wm == p) {
      // C/D layout: col = ni*16 + (l&15); row = mi*16 + (l>>4)*4 + r
#pragma unroll
      for (int mi = 0; mi < 4; ++mi)
#pragma unroll
        for (int ni = 0; ni < 4; ++ni) {
          const int col = wn * 64 + ni * 16 + (l & 15);
          const int trow = mi * 16 + (l >> 4) * 4;
#pragma unroll
          for (int r = 0; r < 4; ++r)
            scanbuf[(trow + r) * 132 + col] = acc[mi][ni][r];
        }
    }
    __syncthreads();
    if (tid < BN) {
      for (int t = 0; t < 64; ++t) {
        const float c = scanbuf[t * 132 + tid] + b1v;
        memv = memv * 0.9f + c * 0.1f;
        fired = memv > 1.0f;
        if (fired) memv = 0.f;
      }
    }
    __syncthreads();
  }
  if (tid < BN) spk[(long)b * Hsz + hblk + tid] = fired ? 1.0f : 0.0f;
}

// ------- kernel 4: out = spk @ W2 + b2, exploiting spike sparsity -------
__global__ void gemm2_kernel(const float* __restrict__ spk, const float* __restrict__ W2,
                             const float* __restrict__ b2, float* __restrict__ out) {
  __shared__ int s_cnt[256];
  __shared__ int s_off[257];
  __shared__ int s_list[Hsz];
  const int b = blockIdx.x;
  const int tid = threadIdx.x;
  int hs[8];
  int c = 0;
#pragma unroll
  for (int e = 0; e < 8; ++e) {
    const int h = tid * 8 + e;
    if (spk[(long)b * Hsz + h] > 0.5f) hs[c++] = h;
  }
  s_cnt[tid] = c;
  __syncthreads();
  if (tid == 0) {
    int s = 0;
    for (int i = 0; i < 256; ++i) { s_off[i] = s; s += s_cnt[i]; }
    s_off[256] = s;
  }
  __syncthreads();
  {
    const int base = s_off[tid];
    for (int i = 0; i < c; ++i) s_list[base + i] = hs[i];
  }
  __syncthreads();
  const int total = s_off[256];
#pragma unroll
  for (int q = 0; q < 4; ++q) {
    const int o = q * 256 + tid;
    float v = b2[o];
    for (int i = 0; i < total; ++i) v += W2[(long)s_list[i] * Osz + o];
    out[(long)b * Osz + o] = v;
  }
}

extern "C" void kernel_launch(void* const* d_in, const int* in_sizes, int n_in,
                              void* d_out, int out_size, void* d_ws, size_t ws_size,
                              hipStream_t stream) {
  const float* x = (const float*)d_in[0];
  const float* W1 = (const float*)d_in[1];
  const float* b1 = (const float*)d_in[2];
  const float* W2 = (const float*)d_in[3];
  const float* b2 = (const float*)d_in[4];
  float* out = (float*)d_out;

  // workspace layout (total ~72.5 MB)
  unsigned short* xh = (unsigned short*)d_ws;           // [16384][1024] bf16
  unsigned short* xl = xh + (long)Bsz * Tsz * Isz;      // [16384][1024]
  unsigned short* wh = xl + (long)Bsz * Tsz * Isz;      // [2048][1024] (W1^T)
  unsigned short* wl = wh + (long)Hsz * Isz;            // [2048][1024]
  float* spk = (float*)(wl + (long)Hsz * Isz);          // [64][2048]

  split_x_kernel<<<(Bsz * Tsz * Isz) / (256 * 4), 256, 0, stream>>>(x, xh, xl);
  w1_transpose_split_kernel<<<dim3(Hsz / 32, Isz / 32), 256, 0, stream>>>(W1, wh, wl);
  gemm1_scan_kernel<<<dim3(16, 64), 512, 0, stream>>>(xh, xl, wh, wl, b1, spk);
  gemm2_kernel<<<Bsz, 256, 0, stream>>>(spk, W2, b2, out);
}

// Round 3
// 208.756 us; speedup vs baseline: 1.1083x; 1.0977x over previous
//
#include <hip/hip_runtime.h>

// SpikingNeuralNetwork: fc1 (split-bf16x3 MFMA GEMM, fused LIF scan) + sparse fc2.
// R3: 256x256 tile (full batch per block), 32x32x16 MFMA, product-major 4-phase
// schedule, double-buffered LDS (128KB), counted vmcnt(4), XOR swizzle, setprio.

typedef __attribute__((ext_vector_type(16))) float f32x16;
typedef __attribute__((ext_vector_type(8))) short s16x8;

#define GPTR(p) ((const __attribute__((address_space(1))) void*)(p))
#define SPTR(p) ((__attribute__((address_space(3))) void*)(p))

static constexpr int Bsz = 64, Tsz = 256, Isz = 1024, Hsz = 2048, Osz = 1024;
static constexpr int BK = 32;          // fp32-k per K-tile
static constexpr int NKT = Isz / BK;   // 32
// buffer regions (ushort elements): Ah, Al, Bh, Bl each 256x32
static constexpr int AH_OFF = 0, AL_OFF = 8192, BH_OFF = 16384, BL_OFF = 24576;
static constexpr int BUFEL = 32768;    // 64KB per K-tile buffer, x2 = 128KB

__device__ __forceinline__ unsigned short f2bf(float f) {
  unsigned u = __float_as_uint(f);
  u += 0x7FFFu + ((u >> 16) & 1u);
  return (unsigned short)(u >> 16);
}
__device__ __forceinline__ float bf2f(unsigned short h) {
  return __uint_as_float(((unsigned)h) << 16);
}

// ---------------- kernel 1: split x into hi/lo bf16 ----------------
__global__ void split_x_kernel(const float* __restrict__ x,
                               unsigned short* __restrict__ hi,
                               unsigned short* __restrict__ lo) {
  const long i = (long)blockIdx.x * 256 + threadIdx.x;
  const float4 v = ((const float4*)x)[i];
  const unsigned short hx = f2bf(v.x), hy = f2bf(v.y), hz = f2bf(v.z), hw = f2bf(v.w);
  ushort4 H, L;
  H.x = hx; H.y = hy; H.z = hz; H.w = hw;
  L.x = f2bf(v.x - bf2f(hx));
  L.y = f2bf(v.y - bf2f(hy));
  L.z = f2bf(v.z - bf2f(hz));
  L.w = f2bf(v.w - bf2f(hw));
  ((ushort4*)hi)[i] = H;
  ((ushort4*)lo)[i] = L;
}

// ------- kernel 2: W1 [I][H] -> transposed bf16 hi/lo [H][I] -------
__global__ void w1_transpose_split_kernel(const float* __restrict__ W1,
                                          unsigned short* __restrict__ wh,
                                          unsigned short* __restrict__ wl) {
  __shared__ float tile[32][33];
  const int h0 = blockIdx.x * 32;
  const int i0 = blockIdx.y * 32;
  const int c = threadIdx.x & 31;
  const int r4 = threadIdx.x >> 5;
#pragma unroll
  for (int s = 0; s < 4; ++s) {
    const int r = r4 + s * 8;
    tile[r][c] = W1[(long)(i0 + r) * Hsz + h0 + c];
  }
  __syncthreads();
#pragma unroll
  for (int s = 0; s < 4; ++s) {
    const int hr = r4 + s * 8;
    const float v = tile[c][hr];
    const unsigned short hh = f2bf(v);
    wh[(long)(h0 + hr) * Isz + i0 + c] = hh;
    wl[(long)(h0 + hr) * Isz + i0 + c] = f2bf(v - bf2f(hh));
  }
}

// ---- kernel 3: fused GEMM1 (split-bf16x3, 32x32x16 MFMA) + LIF scan ----
// grid (8 hblk, 64 b), 512 threads = 8 waves (2M x 4N); wave tile 128x64.
__global__ __launch_bounds__(512, 2) void gemm1_scan_kernel(
    const unsigned short* __restrict__ xh, const unsigned short* __restrict__ xl,
    const unsigned short* __restrict__ wth, const unsigned short* __restrict__ wtl,
    const float* __restrict__ b1, float* __restrict__ spk) {
  __shared__ __align__(16) unsigned short lds[2 * BUFEL];  // 128KB

  const int tid = threadIdx.x;
  const int l = tid & 63;
  const int w = tid >> 6;
  const int wm = w >> 2;  // 0..1 (M: t rows)
  const int wn = w & 3;   // 0..3 (N: h cols)
  const int b = blockIdx.y;
  const int hb = blockIdx.x * 256;

  // --- staging source addressing (linear LDS dest + inverse-swizzled source) ---
  // LDS row = 32 ushort = 64B = 4 chunks of 16B; stored chunk' = chunk ^ ((row>>1)&3)
  const int srow = tid >> 2;                          // 0..127
  const int gch8 = ((tid & 3) ^ ((tid >> 3) & 3)) * 8;
  const long aoff0 = (long)(b * Tsz + srow) * Isz + gch8;
  const long aoff1 = (long)(b * Tsz + 128 + srow) * Isz + gch8;
  const long boff0 = (long)(hb + srow) * Isz + gch8;
  const long boff1 = (long)(hb + 128 + srow) * Isz + gch8;
  const unsigned short* gAh0 = xh + aoff0;  const unsigned short* gAh1 = xh + aoff1;
  const unsigned short* gAl0 = xl + aoff0;  const unsigned short* gAl1 = xl + aoff1;
  const unsigned short* gBh0 = wth + boff0; const unsigned short* gBh1 = wth + boff1;
  const unsigned short* gBl0 = wtl + boff0; const unsigned short* gBl1 = wtl + boff1;

#define STG(OFF, G0, G1, KT) do {                                                      \
    unsigned short* d_ = lds + ((KT) & 1) * BUFEL + (OFF) + tid * 8;                   \
    __builtin_amdgcn_global_load_lds(GPTR((G0) + (long)(KT) * BK), SPTR(d_), 16, 0, 0);\
    __builtin_amdgcn_global_load_lds(GPTR((G1) + (long)(KT) * BK), SPTR(d_ + 4096), 16, 0, 0); \
  } while (0)

  // --- fragment read addressing (swizzled): A row = wm*128+mi*32+(l&31), k = ks*16+(l>>5)*8+j
  const int lr = l & 31;
  const int swzf = (l >> 1) & 3;
  const int chK0 = (((l >> 5)) ^ swzf) * 8;      // ks=0 chunk
  const int chK1 = ((2 + (l >> 5)) ^ swzf) * 8;  // ks=1 chunk
  const int abase = (wm * 128 + lr) * 32;
  const int bbase = (wn * 64 + lr) * 32;

  f32x16 acc[4][2];
#pragma unroll
  for (int i = 0; i < 4; ++i)
#pragma unroll
    for (int j = 0; j < 2; ++j) acc[i][j] = (f32x16)(0.f);

#define MM(MI, NI, AF, BF) \
  acc[MI][NI] = __builtin_amdgcn_mfma_f32_32x32x16_bf16(AF, BF, acc[MI][NI], 0, 0, 0)

#define BAR() __builtin_amdgcn_s_barrier()
#define LGKM0() do { asm volatile("s_waitcnt lgkmcnt(0)" ::: "memory");                \
    __builtin_amdgcn_sched_barrier(0); } while (0)

  // --- prologue: stage tile 0 fully, drain once ---
  STG(AH_OFF, gAh0, gAh1, 0);
  STG(BH_OFF, gBh0, gBh1, 0);
  STG(BL_OFF, gBl0, gBl1, 0);
  STG(AL_OFF, gAl0, gAl1, 0);
  asm volatile("s_waitcnt vmcnt(0)" ::: "memory");
  BAR();

  s16x8 Ah0[4], Ah1[4], Al0[4], Al1[4], Bh0[2], Bh1[2], Bl0[2], Bl1[2];

  for (int kt = 0; kt < NKT; ++kt) {
    const unsigned short* p = lds + (kt & 1) * BUFEL;
    const bool st = (kt + 1) < NKT;

    // ---- phase 0: read Ah(ks0), Bh(ks0+ks1); stage Ah(kt+1); MFMA hihi ks0 (8) ----
#pragma unroll
    for (int mi = 0; mi < 4; ++mi)
      Ah0[mi] = *(const s16x8*)(p + AH_OFF + abase + mi * 1024 + chK0);
#pragma unroll
    for (int ni = 0; ni < 2; ++ni) {
      Bh0[ni] = *(const s16x8*)(p + BH_OFF + bbase + ni * 1024 + chK0);
      Bh1[ni] = *(const s16x8*)(p + BH_OFF + bbase + ni * 1024 + chK1);
    }
    if (st) STG(AH_OFF, gAh0, gAh1, kt + 1);
    BAR();
    LGKM0();
    __builtin_amdgcn_s_setprio(1);
    MM(0, 0, Ah0[0], Bh0[0]); MM(0, 1, Ah0[0], Bh0[1]);
    MM(1, 0, Ah0[1], Bh0[0]); MM(1, 1, Ah0[1], Bh0[1]);
    MM(2, 0, Ah0[2], Bh0[0]); MM(2, 1, Ah0[2], Bh0[1]);
    MM(3, 0, Ah0[3], Bh0[0]); MM(3, 1, Ah0[3], Bh0[1]);
    __builtin_amdgcn_s_setprio(0);
    if (st) asm volatile("s_waitcnt vmcnt(4)" ::: "memory");
    else    asm volatile("s_waitcnt vmcnt(2)" ::: "memory");
    BAR();

    // ---- phase 1: read Ah(ks1), Bl(ks0+ks1); stage Bh(kt+1); MFMA hihi ks1 (8) ----
#pragma unroll
    for (int mi = 0; mi < 4; ++mi)
      Ah1[mi] = *(const s16x8*)(p + AH_OFF + abase + mi * 1024 + chK1);
#pragma unroll
    for (int ni = 0; ni < 2; ++ni) {
      Bl0[ni] = *(const s16x8*)(p + BL_OFF + bbase + ni * 1024 + chK0);
      Bl1[ni] = *(const s16x8*)(p + BL_OFF + bbase + ni * 1024 + chK1);
    }
    if (st) STG(BH_OFF, gBh0, gBh1, kt + 1);
    BAR();
    LGKM0();
    __builtin_amdgcn_s_setprio(1);
    MM(0, 0, Ah1[0], Bh1[0]); MM(0, 1, Ah1[0], Bh1[1]);
    MM(1, 0, Ah1[1], Bh1[0]); MM(1, 1, Ah1[1], Bh1[1]);
    MM(2, 0, Ah1[2], Bh1[0]); MM(2, 1, Ah1[2], Bh1[1]);
    MM(3, 0, Ah1[3], Bh1[0]); MM(3, 1, Ah1[3], Bh1[1]);
    __builtin_amdgcn_s_setprio(0);
    if (st) asm volatile("s_waitcnt vmcnt(4)" ::: "memory");
    else    asm volatile("s_waitcnt vmcnt(0)" ::: "memory");
    BAR();

    // ---- phase 2: (no reads); stage Bl(kt+1); MFMA hilo ks0+ks1 (16) ----
    if (st) STG(BL_OFF, gBl0, gBl1, kt + 1);
    BAR();
    LGKM0();
    __builtin_amdgcn_s_setprio(1);
    MM(0, 0, Ah0[0], Bl0[0]); MM(0, 1, Ah0[0], Bl0[1]);
    MM(1, 0, Ah0[1], Bl0[0]); MM(1, 1, Ah0[1], Bl0[1]);
    MM(2, 0, Ah0[2], Bl0[0]); MM(2, 1, Ah0[2], Bl0[1]);
    MM(3, 0, Ah0[3], Bl0[0]); MM(3, 1, Ah0[3], Bl0[1]);
    MM(0, 0, Ah1[0], Bl1[0]); MM(0, 1, Ah1[0], Bl1[1]);
    MM(1, 0, Ah1[1], Bl1[0]); MM(1, 1, Ah1[1], Bl1[1]);
    MM(2, 0, Ah1[2], Bl1[0]); MM(2, 1, Ah1[2], Bl1[1]);
    MM(3, 0, Ah1[3], Bl1[0]); MM(3, 1, Ah1[3], Bl1[1]);
    __builtin_amdgcn_s_setprio(0);
    if (st) asm volatile("s_waitcnt vmcnt(4)" ::: "memory");
    BAR();

    // ---- phase 3: read Al(ks0+ks1); stage Al(kt+1); MFMA lohi (16) ----
#pragma unroll
    for (int mi = 0; mi < 4; ++mi) {
      Al0[mi] = *(const s16x8*)(p + AL_OFF + abase + mi * 1024 + chK0);
      Al1[mi] = *(const s16x8*)(p + AL_OFF + abase + mi * 1024 + chK1);
    }
    if (st) STG(AL_OFF, gAl0, gAl1, kt + 1);
    BAR();
    LGKM0();
    __builtin_amdgcn_s_setprio(1);
    MM(0, 0, Al0[0], Bh0[0]); MM(0, 1, Al0[0], Bh0[1]);
    MM(1, 0, Al0[1], Bh0[0]); MM(1, 1, Al0[1], Bh0[1]);
    MM(2, 0, Al0[2], Bh0[0]); MM(2, 1, Al0[2], Bh0[1]);
    MM(3, 0, Al0[3], Bh0[0]); MM(3, 1, Al0[3], Bh0[1]);
    MM(0, 0, Al1[0], Bh1[0]); MM(0, 1, Al1[0], Bh1[1]);
    MM(1, 0, Al1[1], Bh1[0]); MM(1, 1, Al1[1], Bh1[1]);
    MM(2, 0, Al1[2], Bh1[0]); MM(2, 1, Al1[2], Bh1[1]);
    MM(3, 0, Al1[3], Bh1[0]); MM(3, 1, Al1[3], Bh1[1]);
    __builtin_amdgcn_s_setprio(0);
    if (st) asm volatile("s_waitcnt vmcnt(4)" ::: "memory");
    BAR();
  }

  // ---- LIF scan: 2 rounds x 128 timesteps through LDS ----
  __syncthreads();
  float* scanbuf = reinterpret_cast<float*>(lds);  // [128][256] f32 = 128KB
  float memv = 0.f;
  int fired = 0;
  const float b1v = b1[hb + ((tid < 256) ? tid : 0)];

  for (int rnd = 0; rnd < 2; ++rnd) {
    if (wm == rnd) {
      // C/D 32x32: col(h) = l&31, row(t) = (r&3) + 8*(r>>2) + 4*(l>>5)
#pragma unroll
      for (int mi = 0; mi < 4; ++mi)
#pragma unroll
        for (int ni = 0; ni < 2; ++ni) {
          const int col = wn * 64 + ni * 32 + lr;
#pragma unroll
          for (int r = 0; r < 16; ++r) {
            const int trow = mi * 32 + (r & 3) + 8 * (r >> 2) + 4 * (l >> 5);
            scanbuf[trow * 256 + col] = acc[mi][ni][r];
          }
        }
    }
    __syncthreads();
    if (tid < 256) {
      for (int t = 0; t < 128; ++t) {
        const float c = scanbuf[t * 256 + tid] + b1v;
        memv = memv * 0.9f + c * 0.1f;
        fired = memv > 1.0f;
        if (fired) memv = 0.f;
      }
    }
    __syncthreads();
  }
  if (tid < 256) spk[(long)b * Hsz + hb + tid] = fired ? 1.0f : 0.0f;
}

// ------- kernel 4: out = spk @ W2 + b2, exploiting spike sparsity -------
__global__ void gemm2_kernel(const float* __restrict__ spk, const float* __restrict__ W2,
                             const float* __restrict__ b2, float* __restrict__ out) {
  __shared__ int s_cnt[256];
  __shared__ int s_off[257];
  __shared__ int s_list[Hsz];
  const int b = blockIdx.x;
  const int tid = threadIdx.x;
  int hs[8];
  int c = 0;
#pragma unroll
  for (int e = 0; e < 8; ++e) {
    const int h = tid * 8 + e;
    if (spk[(long)b * Hsz + h] > 0.5f) hs[c++] = h;
  }
  s_cnt[tid] = c;
  __syncthreads();
  if (tid == 0) {
    int s = 0;
    for (int i = 0; i < 256; ++i) { s_off[i] = s; s += s_cnt[i]; }
    s_off[256] = s;
  }
  __syncthreads();
  {
    const int base = s_off[tid];
    for (int i = 0; i < c; ++i) s_list[base + i] = hs[i];
  }
  __syncthreads();
  const int total = s_off[256];
#pragma unroll
  for (int q = 0; q < 4; ++q) {
    const int o = q * 256 + tid;
    float v = b2[o];
    for (int i = 0; i < total; ++i) v += W2[(long)s_list[i] * Osz + o];
    out[(long)b * Osz + o] = v;
  }
}

extern "C" void kernel_launch(void* const* d_in, const int* in_sizes, int n_in,
                              void* d_out, int out_size, void* d_ws, size_t ws_size,
                              hipStream_t stream) {
  const float* x = (const float*)d_in[0];
  const float* W1 = (const float*)d_in[1];
  const float* b1 = (const float*)d_in[2];
  const float* W2 = (const float*)d_in[3];
  const float* b2 = (const float*)d_in[4];
  float* out = (float*)d_out;

  unsigned short* xh = (unsigned short*)d_ws;           // [16384][1024] bf16
  unsigned short* xl = xh + (long)Bsz * Tsz * Isz;
  unsigned short* wh = xl + (long)Bsz * Tsz * Isz;      // [2048][1024] (W1^T)
  unsigned short* wl = wh + (long)Hsz * Isz;
  float* spk = (float*)(wl + (long)Hsz * Isz);          // [64][2048]

  split_x_kernel<<<(Bsz * Tsz * Isz) / (256 * 4), 256, 0, stream>>>(x, xh, xl);
  w1_transpose_split_kernel<<<dim3(Hsz / 32, Isz / 32), 256, 0, stream>>>(W1, wh, wl);
  gemm1_scan_kernel<<<dim3(8, 64), 512, 0, stream>>>(xh, xl, wh, wl, b1, spk);
  gemm2_kernel<<<Bsz, 256, 0, stream>>>(spk, W2, b2, out);
}